// Round 12
// baseline (324.553 us; speedup 1.0000x reference)
//
#include <hip/hip_runtime.h>
#include <hip/hip_bf16.h>
#include <math.h>

#define NN 100000
#define NE 3200000
#define NPAD 100096
#define NB 392        // buckets: dst>>8, 256 nodes each
#define BN 256        // nodes per bucket
#define EPB 4096      // edges per block in scatter pass
#define NBLK 782      // ceil(NE/EPB)
#define SLOT 9728     // slab size per bucket (mean 8163 + 17 sigma)

typedef __attribute__((ext_vector_type(8))) short short8;
typedef __attribute__((ext_vector_type(4))) float floatx4;
typedef __attribute__((ext_vector_type(4))) unsigned uint4v;

// ---------------- bf16 helpers (storage bf16, math fp32) ----------------
__device__ __forceinline__ unsigned short bf16_of(float x) {
    __hip_bfloat16 h = __float2bfloat16(x);  // RNE
    return *(unsigned short*)&h;
}
__device__ __forceinline__ unsigned pack2(float a, float b) {
    return (unsigned)bf16_of(a) | ((unsigned)bf16_of(b) << 16);
}
__device__ __forceinline__ float lo_f(unsigned u) { return __uint_as_float(u << 16); }
__device__ __forceinline__ float hi_f(unsigned u) { return __uint_as_float(u & 0xffff0000u); }
__device__ __forceinline__ void acc8(float* a, uint4v r) {
    a[0] += lo_f(r[0]); a[1] += hi_f(r[0]);
    a[2] += lo_f(r[1]); a[3] += hi_f(r[1]);
    a[4] += lo_f(r[2]); a[5] += hi_f(r[2]);
    a[6] += lo_f(r[3]); a[7] += hi_f(r[3]);
}

// ---------------- pass 1: scatter into fixed-stride bucket slabs ----------------
// Each block: LDS count -> wave0 scan -> ONE global atomicAdd per bucket to
// reserve a contiguous run in the bucket's slab -> LDS-staged scatter ->
// contiguous run write-out.
__global__ __launch_bounds__(512) void scatter_kernel(const int* __restrict__ src,
                                                      const int* __restrict__ dst,
                                                      int* __restrict__ gcur,
                                                      int* __restrict__ staged) {
    __shared__ int cnt[NB];
    __shared__ int lbase[NB + 1];
    __shared__ int gbase[NB];
    __shared__ int sbuf[EPB];               // 16KB: (src<<8)|dlow
    __shared__ unsigned short sbkt[EPB];    // 8KB: bucket id per slot
    int t = threadIdx.x;
    for (int i = t; i < NB; i += 512) cnt[i] = 0;
    __syncthreads();
    int e0 = blockIdx.x * EPB;
    int e1 = min(e0 + EPB, NE);
    int cn = e1 - e0;
    for (int e = e0 + t; e < e1; e += 512) atomicAdd(&cnt[dst[e] >> 8], 1);
    __syncthreads();
    if (t < 64) {  // wave0: exclusive scan of 392 local counts, 7 per lane
        int v[7]; int s = 0;
#pragma unroll
        for (int k = 0; k < 7; ++k) { int idx = t * 7 + k; v[k] = (idx < NB) ? cnt[idx] : 0; s += v[k]; }
        int inc = s;
#pragma unroll
        for (int m = 1; m < 64; m <<= 1) {
            int u = __shfl_up(inc, m, 64);
            if (t >= m) inc += u;
        }
        int run = inc - s;
#pragma unroll
        for (int k = 0; k < 7; ++k) { int idx = t * 7 + k; if (idx < NB) lbase[idx] = run; run += v[k]; }
        if (t == 63) lbase[NB] = inc;  // == cn
    }
    __syncthreads();
    for (int i = t; i < NB; i += 512) {
        int c = cnt[i];
        gbase[i] = i * SLOT + atomicAdd(&gcur[i], c);  // reserve contiguous run
        cnt[i] = lbase[i];                             // rank cursors
    }
    __syncthreads();
    for (int e = e0 + t; e < e1; e += 512) {
        int s = src[e], d = dst[e];
        int bk = d >> 8;
        int r = atomicAdd(&cnt[bk], 1);     // LDS atomic
        sbuf[r] = (s << 8) | (d & (BN - 1));
        sbkt[r] = (unsigned short)bk;
    }
    __syncthreads();
    for (int i = t; i < cn; i += 512) {     // contiguous run write-out
        int bk = sbkt[i];
        staged[gbase[bk] + i - lbase[bk]] = sbuf[i];
    }
}

// ---------------- pass 2: per-bucket fine counting sort + node ranges + dis ----------------
__global__ __launch_bounds__(1024) void fine_kernel(const int* __restrict__ staged,
                                                    const int* __restrict__ gcur,
                                                    int2* __restrict__ offs2,
                                                    float* __restrict__ dis,
                                                    int* __restrict__ csr_src) {
    __shared__ int hist[BN];
    __shared__ int offs[BN];
    __shared__ int cur[BN];
    int t = threadIdx.x, j = blockIdx.x;
    int bb = j * SLOT;
    int be = bb + gcur[j];
    for (int i = t; i < BN; i += 1024) hist[i] = 0;
    __syncthreads();
    for (int e = bb + t; e < be; e += 1024) atomicAdd(&hist[staged[e] & (BN - 1)], 1);
    __syncthreads();
    if (t < 64) {  // wave0: exclusive scan of 256 counts, 4 per lane
        int v[4]; int s = 0;
#pragma unroll
        for (int k = 0; k < 4; ++k) { v[k] = hist[t * 4 + k]; s += v[k]; }
        int inc = s;
#pragma unroll
        for (int m = 1; m < 64; m <<= 1) {
            int u = __shfl_up(inc, m, 64);
            if (t >= m) inc += u;
        }
        int run = inc - s;
#pragma unroll
        for (int k = 0; k < 4; ++k) { offs[t * 4 + k] = run; run += v[k]; }
    }
    __syncthreads();
    for (int l = t; l < BN; l += 1024) {
        cur[l] = offs[l];
        int n = j * BN + l;
        if (n < NN) {
            int st = bb + offs[l];
            offs2[n] = make_int2(st, st + hist[l]);
            dis[n] = rsqrtf((float)hist[l] + 1.0f);
        }
    }
    __syncthreads();
    for (int e = bb + t; e < be; e += 1024) {
        int p = staged[e];
        int r = atomicAdd(&cur[p & (BN - 1)], 1);  // LDS atomic
        csr_src[bb + r] = p >> 8;
    }
}

// ---------------- matmul 1 (MFMA): ys1 = bf16(dis * (x @ W1)) ----------------
__global__ __launch_bounds__(256) void mm1_kernel(const float* __restrict__ x,
                                                  const float* __restrict__ W,
                                                  const float* __restrict__ dis,
                                                  unsigned short* __restrict__ y) {
    __shared__ unsigned short Wt[64][136];  // W^T bf16: [n][k], pad 8 shorts
    int t = threadIdx.x;
    for (int i = t; i < 128 * 64; i += 256) {
        int k = i >> 6, n = i & 63;
        Wt[n][k] = bf16_of(W[i]);
    }
    __syncthreads();
    int wave = t >> 6, lane = t & 63;
    int quad = lane >> 4, n16 = lane & 15;
    short8 bfr[4][4];  // [kstep][coltile]
#pragma unroll
    for (int s = 0; s < 4; ++s)
#pragma unroll
        for (int tt = 0; tt < 4; ++tt)
            bfr[s][tt] = *(const short8*)&Wt[tt * 16 + n16][s * 32 + quad * 8];
    int tile0 = (blockIdx.x * 4 + wave) * 4;
#pragma unroll 1
    for (int it = 0; it < 4; ++it) {
        int tile = tile0 + it;
        if (tile >= 6250) break;
        int m0 = tile * 16;
        const float* xp = x + (size_t)(m0 + n16) * 128 + quad * 8;
        floatx4 acc0 = {0,0,0,0}, acc1 = {0,0,0,0}, acc2 = {0,0,0,0}, acc3 = {0,0,0,0};
#pragma unroll
        for (int s = 0; s < 4; ++s) {
            float4 lo = *(const float4*)(xp + s * 32);
            float4 hi = *(const float4*)(xp + s * 32 + 4);
            short8 a;
            a[0] = (short)bf16_of(lo.x); a[1] = (short)bf16_of(lo.y);
            a[2] = (short)bf16_of(lo.z); a[3] = (short)bf16_of(lo.w);
            a[4] = (short)bf16_of(hi.x); a[5] = (short)bf16_of(hi.y);
            a[6] = (short)bf16_of(hi.z); a[7] = (short)bf16_of(hi.w);
            acc0 = __builtin_amdgcn_mfma_f32_16x16x32_bf16(a, bfr[s][0], acc0, 0, 0, 0);
            acc1 = __builtin_amdgcn_mfma_f32_16x16x32_bf16(a, bfr[s][1], acc1, 0, 0, 0);
            acc2 = __builtin_amdgcn_mfma_f32_16x16x32_bf16(a, bfr[s][2], acc2, 0, 0, 0);
            acc3 = __builtin_amdgcn_mfma_f32_16x16x32_bf16(a, bfr[s][3], acc3, 0, 0, 0);
        }
#pragma unroll
        for (int r = 0; r < 4; ++r) {
            int ro = m0 + quad * 4 + r;
            float sc = dis[ro];
            unsigned short* yp = y + (size_t)ro * 64 + n16;
            yp[0]  = bf16_of(acc0[r] * sc);
            yp[16] = bf16_of(acc1[r] * sc);
            yp[32] = bf16_of(acc2[r] * sc);
            yp[48] = bf16_of(acc3[r] * sc);
        }
    }
}

// ---------------- fused layer-1 aggregate + layer-2 matmul ----------------
__global__ __launch_bounds__(256) void agg64mm2_kernel(const uint4v* __restrict__ ys4,
                                                       const float* __restrict__ dis,
                                                       const int2* __restrict__ offs2,
                                                       const int* __restrict__ csr_src,
                                                       const float* __restrict__ b1,
                                                       const float* __restrict__ W2,
                                                       unsigned int* __restrict__ ys2) {
    __shared__ float w2s[64 * 32];      // 8KB fp32, [k][n] row-major
    __shared__ float hbuf[32 * 68];     // 8.5KB: 32 nodes x 64 k, stride 68 (bank-spread)
    int t = threadIdx.x;
    for (int i = t; i < 2048; i += 256) w2s[i] = W2[i];
    __syncthreads();
    int tid = blockIdx.x * 256 + t;
    int nd = tid >> 3, c = tid & 7;     // grid exact: nd < NN always
    int2 se = offs2[nd];
    int start = se.x, end = se.y;
    float acc[8] = {0, 0, 0, 0, 0, 0, 0, 0};
    acc8(acc, ys4[(size_t)nd * 8 + c]);  // self-loop term
    int i = start;
    int n8 = start + ((end - start) & ~7);
    for (; i < n8; i += 8) {
        int s0 = csr_src[i],     s1 = csr_src[i + 1], s2 = csr_src[i + 2], s3 = csr_src[i + 3];
        int s4 = csr_src[i + 4], s5 = csr_src[i + 5], s6 = csr_src[i + 6], s7 = csr_src[i + 7];
        uint4v r0 = ys4[(size_t)s0 * 8 + c];
        uint4v r1 = ys4[(size_t)s1 * 8 + c];
        uint4v r2 = ys4[(size_t)s2 * 8 + c];
        uint4v r3 = ys4[(size_t)s3 * 8 + c];
        uint4v r4 = ys4[(size_t)s4 * 8 + c];
        uint4v r5 = ys4[(size_t)s5 * 8 + c];
        uint4v r6 = ys4[(size_t)s6 * 8 + c];
        uint4v r7 = ys4[(size_t)s7 * 8 + c];
        acc8(acc, r0); acc8(acc, r1); acc8(acc, r2); acc8(acc, r3);
        acc8(acc, r4); acc8(acc, r5); acc8(acc, r6); acc8(acc, r7);
    }
    for (; i < end; ++i) acc8(acc, ys4[(size_t)csr_src[i] * 8 + c]);
    float ds = dis[nd];
    const float4 bv0 = *(const float4*)&b1[c * 8];
    const float4 bv1 = *(const float4*)&b1[c * 8 + 4];
    // h row (fp32, bias + relu) -> per-wave LDS exchange (same-wave, no barrier)
    float* hrow = &hbuf[(t >> 3) * 68];
    float4 h0, h1;
    h0.x = fmaxf(fmaf(ds, acc[0], bv0.x), 0.f);
    h0.y = fmaxf(fmaf(ds, acc[1], bv0.y), 0.f);
    h0.z = fmaxf(fmaf(ds, acc[2], bv0.z), 0.f);
    h0.w = fmaxf(fmaf(ds, acc[3], bv0.w), 0.f);
    h1.x = fmaxf(fmaf(ds, acc[4], bv1.x), 0.f);
    h1.y = fmaxf(fmaf(ds, acc[5], bv1.y), 0.f);
    h1.z = fmaxf(fmaf(ds, acc[6], bv1.z), 0.f);
    h1.w = fmaxf(fmaf(ds, acc[7], bv1.w), 0.f);
    *(float4*)&hrow[c * 8]     = h0;
    *(float4*)&hrow[c * 8 + 4] = h1;
    // z[c*4 .. c*4+3] = ds * sum_k h[k] * W2[k][n]
    float p0 = 0.f, p1 = 0.f, p2 = 0.f, p3 = 0.f;
#pragma unroll 8
    for (int k = 0; k < 64; ++k) {
        float hk = hrow[k];
        const float4 wr = *(const float4*)&w2s[k * 32 + c * 4];
        p0 = fmaf(hk, wr.x, p0);
        p1 = fmaf(hk, wr.y, p1);
        p2 = fmaf(hk, wr.z, p2);
        p3 = fmaf(hk, wr.w, p3);
    }
    p0 *= ds; p1 *= ds; p2 *= ds; p3 *= ds;
    unsigned int* zp = ys2 + (size_t)nd * 16 + c * 2;  // 32 bf16 = 16 uints per node
    zp[0] = pack2(p0, p1);
    zp[1] = pack2(p2, p3);
}

// ---------------- fused gather-aggregate, dim 32 bf16 -> z bf16, unroll 8 ----------------
__global__ __launch_bounds__(256) void agg32_kernel(const uint4v* __restrict__ ys4,
                                                    const float* __restrict__ dis,
                                                    const int2* __restrict__ offs2,
                                                    const int* __restrict__ csr_src,
                                                    const float* __restrict__ b,
                                                    uint4v* __restrict__ z4) {
    int tid = blockIdx.x * 256 + threadIdx.x;
    int nd = tid >> 2, c = tid & 3;
    if (nd >= NN) return;
    int2 se = offs2[nd];
    int start = se.x, end = se.y;
    float acc[8] = {0, 0, 0, 0, 0, 0, 0, 0};
    acc8(acc, ys4[(size_t)nd * 4 + c]);
    int i = start;
    int n8 = start + ((end - start) & ~7);
    for (; i < n8; i += 8) {
        int s0 = csr_src[i],     s1 = csr_src[i + 1], s2 = csr_src[i + 2], s3 = csr_src[i + 3];
        int s4 = csr_src[i + 4], s5 = csr_src[i + 5], s6 = csr_src[i + 6], s7 = csr_src[i + 7];
        uint4v r0 = ys4[(size_t)s0 * 4 + c];
        uint4v r1 = ys4[(size_t)s1 * 4 + c];
        uint4v r2 = ys4[(size_t)s2 * 4 + c];
        uint4v r3 = ys4[(size_t)s3 * 4 + c];
        uint4v r4 = ys4[(size_t)s4 * 4 + c];
        uint4v r5 = ys4[(size_t)s5 * 4 + c];
        uint4v r6 = ys4[(size_t)s6 * 4 + c];
        uint4v r7 = ys4[(size_t)s7 * 4 + c];
        acc8(acc, r0); acc8(acc, r1); acc8(acc, r2); acc8(acc, r3);
        acc8(acc, r4); acc8(acc, r5); acc8(acc, r6); acc8(acc, r7);
    }
    for (; i < end; ++i) acc8(acc, ys4[(size_t)csr_src[i] * 4 + c]);
    float ds = dis[nd];
    const float4 bv0 = *(const float4*)&b[c * 8];
    const float4 bv1 = *(const float4*)&b[c * 8 + 4];
    uint4v o;
    o[0] = pack2(fmaf(ds, acc[0], bv0.x), fmaf(ds, acc[1], bv0.y));
    o[1] = pack2(fmaf(ds, acc[2], bv0.z), fmaf(ds, acc[3], bv0.w));
    o[2] = pack2(fmaf(ds, acc[4], bv1.x), fmaf(ds, acc[5], bv1.y));
    o[3] = pack2(fmaf(ds, acc[6], bv1.z), fmaf(ds, acc[7], bv1.w));
    z4[(size_t)nd * 4 + c] = o;
}

// ---------------- decode: sigmoid(dot(z[src], z[dst])), 4 lanes/edge, bf16 z ---------
__global__ __launch_bounds__(256) void decode_kernel(const uint4v* __restrict__ z4,
                                                     const int* __restrict__ src,
                                                     const int* __restrict__ dst,
                                                     float* __restrict__ out) {
    int tid = blockIdx.x * 256 + threadIdx.x;
    int e = tid >> 2, k = tid & 3;
    if (e >= NE) return;
    int s = src[e], d = dst[e];
    uint4v ra = z4[(size_t)s * 4 + k];
    uint4v rb = z4[(size_t)d * 4 + k];
    float acc;
    acc  = lo_f(ra[0]) * lo_f(rb[0]) + hi_f(ra[0]) * hi_f(rb[0]);
    acc += lo_f(ra[1]) * lo_f(rb[1]) + hi_f(ra[1]) * hi_f(rb[1]);
    acc += lo_f(ra[2]) * lo_f(rb[2]) + hi_f(ra[2]) * hi_f(rb[2]);
    acc += lo_f(ra[3]) * lo_f(rb[3]) + hi_f(ra[3]) * hi_f(rb[3]);
#pragma unroll
    for (int m = 2; m >= 1; m >>= 1) acc += __shfl_xor(acc, m, 4);
    if (k == 0) out[e] = 1.0f / (1.0f + expf(-acc));
}

// ---------------- launcher ----------------
extern "C" void kernel_launch(void* const* d_in, const int* in_sizes, int n_in,
                              void* d_out, int out_size, void* d_ws, size_t ws_size,
                              hipStream_t stream) {
    const float* emb = (const float*)d_in[0];
    const float* W1  = (const float*)d_in[1];
    const float* b1  = (const float*)d_in[2];
    const float* W2  = (const float*)d_in[3];
    const float* b2  = (const float*)d_in[4];
    const int*   ei  = (const int*)d_in[5];
    const int* src = ei;
    const int* dst = ei + NE;
    float* out = (float*)d_out;

    // workspace layout
    char* w = (char*)d_ws;
    int2*  offs2       = (int2*)w;          w += (size_t)NPAD * 8;         // 800KB
    float* dis         = (float*)w;         w += (size_t)NPAD * 4;
    int*   gcur        = (int*)w;           w += 2048;                     // NB cursors
    int*   csr_src     = (int*)w;           w += (size_t)NB * SLOT * 4;    // 15.3MB
    int*   staged      = (int*)w;           w += (size_t)NB * SLOT * 4;    // 15.3MB packed
    unsigned short* ysbuf = (unsigned short*)w; w += (size_t)NN * 64 * 2;  // 12.8MB bf16
    unsigned short* ys2 = (unsigned short*)w;                              // 6.4MB bf16
    unsigned short* ys1 = ysbuf;
    unsigned short* z   = ysbuf;            // overlays dead ys1 after agg64mm2

    // CSR build — 2 kernels: slab-reserving scatter + fine counting sort
    hipMemsetAsync(gcur, 0, NB * 4, stream);
    scatter_kernel<<<NBLK, 512, 0, stream>>>(src, dst, gcur, staged);
    fine_kernel<<<NB, 1024, 0, stream>>>(staged, gcur, offs2, dis, csr_src);

    // layer 1 matmul
    mm1_kernel<<<391, 256, 0, stream>>>(emb, W1, dis, ys1);
    // fused: layer-1 aggregate (+bias,relu) + layer-2 matmul -> ys2
    agg64mm2_kernel<<<(NN * 8) / 256, 256, 0, stream>>>((const uint4v*)ys1, dis, offs2, csr_src,
                                                        b1, W2, (unsigned int*)ys2);
    // layer-2 aggregate -> z (overlays dead ys1)
    agg32_kernel<<<(NN * 4 + 255) / 256, 256, 0, stream>>>((const uint4v*)ys2, dis, offs2, csr_src, b2, (uint4v*)z);

    // decode
    decode_kernel<<<(NE * 4) / 256, 256, 0, stream>>>((const uint4v*)z, src, dst, out);
}

// Round 13
// 323.171 us; speedup vs baseline: 1.0043x; 1.0043x over previous
//
#include <hip/hip_runtime.h>
#include <hip/hip_bf16.h>
#include <math.h>

#define NN 100000
#define NE 3200000
#define NPAD 100096
#define NB 392        // buckets: dst>>8, 256 nodes each
#define BN 256        // nodes per bucket
#define EPB 4096      // edges per block in scatter pass
#define NBLK 782      // ceil(NE/EPB)
#define SLOT 9728     // slab size per bucket (mean 8163 + 17 sigma)
#define MMBLK 391     // mm1 blocks appended to scatter grid (16 tiles each)

typedef __attribute__((ext_vector_type(8))) short short8;
typedef __attribute__((ext_vector_type(4))) float floatx4;
typedef __attribute__((ext_vector_type(4))) unsigned uint4v;

// ---------------- bf16 helpers (storage bf16, math fp32) ----------------
__device__ __forceinline__ unsigned short bf16_of(float x) {
    __hip_bfloat16 h = __float2bfloat16(x);  // RNE
    return *(unsigned short*)&h;
}
__device__ __forceinline__ unsigned pack2(float a, float b) {
    return (unsigned)bf16_of(a) | ((unsigned)bf16_of(b) << 16);
}
__device__ __forceinline__ float lo_f(unsigned u) { return __uint_as_float(u << 16); }
__device__ __forceinline__ float hi_f(unsigned u) { return __uint_as_float(u & 0xffff0000u); }
__device__ __forceinline__ void acc8(float* a, uint4v r) {
    a[0] += lo_f(r[0]); a[1] += hi_f(r[0]);
    a[2] += lo_f(r[1]); a[3] += hi_f(r[1]);
    a[4] += lo_f(r[2]); a[5] += hi_f(r[2]);
    a[6] += lo_f(r[3]); a[7] += hi_f(r[3]);
}
// scaled accumulate: a += d * r  (for unscaled ys1 rows, d = dis[src])
__device__ __forceinline__ void acc8s(float* a, uint4v r, float d) {
    a[0] = fmaf(lo_f(r[0]), d, a[0]); a[1] = fmaf(hi_f(r[0]), d, a[1]);
    a[2] = fmaf(lo_f(r[1]), d, a[2]); a[3] = fmaf(hi_f(r[1]), d, a[3]);
    a[4] = fmaf(lo_f(r[2]), d, a[4]); a[5] = fmaf(hi_f(r[2]), d, a[5]);
    a[6] = fmaf(lo_f(r[3]), d, a[6]); a[7] = fmaf(hi_f(r[3]), d, a[7]);
}

// ---------------- merged pass: scatter (blocks 0..NBLK-1) + mm1 (blocks NBLK..) --------
// Scatter: LDS count -> wave0 scan -> one global atomicAdd per bucket to reserve a
// contiguous slab run -> LDS-staged scatter -> contiguous write-out.
// mm1: ys1 = bf16(x @ W1) UNSCALED (dis applied later in agg64mm2) -> no dependency
// on the CSR build, so its MFMA blocks overlap scatter's latency-bound blocks.
__global__ __launch_bounds__(512) void scatter_mm1_kernel(const int* __restrict__ src,
                                                          const int* __restrict__ dst,
                                                          int* __restrict__ gcur,
                                                          int* __restrict__ staged,
                                                          const float* __restrict__ x,
                                                          const float* __restrict__ W1,
                                                          unsigned short* __restrict__ y) {
    __shared__ union {
        struct {
            int cnt[NB];
            int lbase[NB + 1];
            int gbase[NB];
            int sbuf[EPB];               // 16KB: (src<<8)|dlow
            unsigned short sbkt[EPB];    // 8KB
        } sc;
        unsigned short Wt[64][136];      // 17KB: W1^T bf16 [n][k], pad 8
    } sm;
    int t = threadIdx.x;
    if (blockIdx.x < NBLK) {
        // ---------------- scatter branch ----------------
        for (int i = t; i < NB; i += 512) sm.sc.cnt[i] = 0;
        __syncthreads();
        int e0 = blockIdx.x * EPB;
        int e1 = min(e0 + EPB, NE);
        int cn = e1 - e0;
        for (int e = e0 + t; e < e1; e += 512) atomicAdd(&sm.sc.cnt[dst[e] >> 8], 1);
        __syncthreads();
        if (t < 64) {  // wave0: exclusive scan of 392 local counts, 7 per lane
            int v[7]; int s = 0;
#pragma unroll
            for (int k = 0; k < 7; ++k) { int idx = t * 7 + k; v[k] = (idx < NB) ? sm.sc.cnt[idx] : 0; s += v[k]; }
            int inc = s;
#pragma unroll
            for (int m = 1; m < 64; m <<= 1) {
                int u = __shfl_up(inc, m, 64);
                if (t >= m) inc += u;
            }
            int run = inc - s;
#pragma unroll
            for (int k = 0; k < 7; ++k) { int idx = t * 7 + k; if (idx < NB) sm.sc.lbase[idx] = run; run += v[k]; }
            if (t == 63) sm.sc.lbase[NB] = inc;  // == cn
        }
        __syncthreads();
        for (int i = t; i < NB; i += 512) {
            int c = sm.sc.cnt[i];
            sm.sc.gbase[i] = i * SLOT + atomicAdd(&gcur[i], c);  // reserve run
            sm.sc.cnt[i] = sm.sc.lbase[i];                       // rank cursors
        }
        __syncthreads();
        for (int e = e0 + t; e < e1; e += 512) {
            int s = src[e], d = dst[e];
            int bk = d >> 8;
            int r = atomicAdd(&sm.sc.cnt[bk], 1);     // LDS atomic
            sm.sc.sbuf[r] = (s << 8) | (d & (BN - 1));
            sm.sc.sbkt[r] = (unsigned short)bk;
        }
        __syncthreads();
        for (int i = t; i < cn; i += 512) {     // contiguous run write-out
            int bk = sm.sc.sbkt[i];
            staged[sm.sc.gbase[bk] + i - sm.sc.lbase[bk]] = sm.sc.sbuf[i];
        }
    } else {
        // ---------------- mm1 branch (8 waves, 2 tiles each) ----------------
        for (int i = t; i < 128 * 64; i += 512) {
            int k = i >> 6, n = i & 63;
            sm.Wt[n][k] = bf16_of(W1[i]);
        }
        __syncthreads();
        int wave = t >> 6, lane = t & 63;
        int quad = lane >> 4, n16 = lane & 15;
        short8 bfr[4][4];  // [kstep][coltile]
#pragma unroll
        for (int s = 0; s < 4; ++s)
#pragma unroll
            for (int tt = 0; tt < 4; ++tt)
                bfr[s][tt] = *(const short8*)&sm.Wt[tt * 16 + n16][s * 32 + quad * 8];
        int tile0 = ((blockIdx.x - NBLK) * 8 + wave) * 2;
#pragma unroll 1
        for (int it = 0; it < 2; ++it) {
            int tile = tile0 + it;
            if (tile >= 6250) break;
            int m0 = tile * 16;
            const float* xp = x + (size_t)(m0 + n16) * 128 + quad * 8;
            floatx4 acc0 = {0,0,0,0}, acc1 = {0,0,0,0}, acc2 = {0,0,0,0}, acc3 = {0,0,0,0};
#pragma unroll
            for (int s = 0; s < 4; ++s) {
                float4 lo = *(const float4*)(xp + s * 32);
                float4 hi = *(const float4*)(xp + s * 32 + 4);
                short8 a;
                a[0] = (short)bf16_of(lo.x); a[1] = (short)bf16_of(lo.y);
                a[2] = (short)bf16_of(lo.z); a[3] = (short)bf16_of(lo.w);
                a[4] = (short)bf16_of(hi.x); a[5] = (short)bf16_of(hi.y);
                a[6] = (short)bf16_of(hi.z); a[7] = (short)bf16_of(hi.w);
                acc0 = __builtin_amdgcn_mfma_f32_16x16x32_bf16(a, bfr[s][0], acc0, 0, 0, 0);
                acc1 = __builtin_amdgcn_mfma_f32_16x16x32_bf16(a, bfr[s][1], acc1, 0, 0, 0);
                acc2 = __builtin_amdgcn_mfma_f32_16x16x32_bf16(a, bfr[s][2], acc2, 0, 0, 0);
                acc3 = __builtin_amdgcn_mfma_f32_16x16x32_bf16(a, bfr[s][3], acc3, 0, 0, 0);
            }
#pragma unroll
            for (int r = 0; r < 4; ++r) {
                int ro = m0 + quad * 4 + r;
                unsigned short* yp = y + (size_t)ro * 64 + n16;
                yp[0]  = bf16_of(acc0[r]);
                yp[16] = bf16_of(acc1[r]);
                yp[32] = bf16_of(acc2[r]);
                yp[48] = bf16_of(acc3[r]);
            }
        }
    }
}

// ---------------- pass 2: per-bucket fine counting sort + node ranges + dis ----------------
__global__ __launch_bounds__(1024) void fine_kernel(const int* __restrict__ staged,
                                                    const int* __restrict__ gcur,
                                                    int2* __restrict__ offs2,
                                                    float* __restrict__ dis,
                                                    int* __restrict__ csr_src) {
    __shared__ int hist[BN];
    __shared__ int offs[BN];
    __shared__ int cur[BN];
    int t = threadIdx.x, j = blockIdx.x;
    int bb = j * SLOT;
    int be = bb + gcur[j];
    for (int i = t; i < BN; i += 1024) hist[i] = 0;
    __syncthreads();
    for (int e = bb + t; e < be; e += 1024) atomicAdd(&hist[staged[e] & (BN - 1)], 1);
    __syncthreads();
    if (t < 64) {  // wave0: exclusive scan of 256 counts, 4 per lane
        int v[4]; int s = 0;
#pragma unroll
        for (int k = 0; k < 4; ++k) { v[k] = hist[t * 4 + k]; s += v[k]; }
        int inc = s;
#pragma unroll
        for (int m = 1; m < 64; m <<= 1) {
            int u = __shfl_up(inc, m, 64);
            if (t >= m) inc += u;
        }
        int run = inc - s;
#pragma unroll
        for (int k = 0; k < 4; ++k) { offs[t * 4 + k] = run; run += v[k]; }
    }
    __syncthreads();
    for (int l = t; l < BN; l += 1024) {
        cur[l] = offs[l];
        int n = j * BN + l;
        if (n < NN) {
            int st = bb + offs[l];
            offs2[n] = make_int2(st, st + hist[l]);
            dis[n] = rsqrtf((float)hist[l] + 1.0f);
        }
    }
    __syncthreads();
    for (int e = bb + t; e < be; e += 1024) {
        int p = staged[e];
        int r = atomicAdd(&cur[p & (BN - 1)], 1);  // LDS atomic
        csr_src[bb + r] = p >> 8;
    }
}

// ---------------- fused layer-1 aggregate + layer-2 matmul ----------------
// ys1 rows are UNSCALED; dis[src] applied at gather time (dis is 400KB, L2-resident).
__global__ __launch_bounds__(256) void agg64mm2_kernel(const uint4v* __restrict__ ys4,
                                                       const float* __restrict__ dis,
                                                       const int2* __restrict__ offs2,
                                                       const int* __restrict__ csr_src,
                                                       const float* __restrict__ b1,
                                                       const float* __restrict__ W2,
                                                       unsigned int* __restrict__ ys2) {
    __shared__ float w2s[64 * 32];      // 8KB fp32, [k][n] row-major
    __shared__ float hbuf[32 * 68];     // 8.5KB: 32 nodes x 64 k, stride 68 (bank-spread)
    int t = threadIdx.x;
    for (int i = t; i < 2048; i += 256) w2s[i] = W2[i];
    __syncthreads();
    int tid = blockIdx.x * 256 + t;
    int nd = tid >> 3, c = tid & 7;     // grid exact: nd < NN always
    int2 se = offs2[nd];
    int start = se.x, end = se.y;
    float acc[8] = {0, 0, 0, 0, 0, 0, 0, 0};
    float dnd = dis[nd];
    acc8s(acc, ys4[(size_t)nd * 8 + c], dnd);  // self-loop term (x dis[nd])
    int i = start;
    int n8 = start + ((end - start) & ~7);
    for (; i < n8; i += 8) {
        int s0 = csr_src[i],     s1 = csr_src[i + 1], s2 = csr_src[i + 2], s3 = csr_src[i + 3];
        int s4 = csr_src[i + 4], s5 = csr_src[i + 5], s6 = csr_src[i + 6], s7 = csr_src[i + 7];
        float d0 = dis[s0], d1 = dis[s1], d2 = dis[s2], d3 = dis[s3];
        float d4 = dis[s4], d5 = dis[s5], d6 = dis[s6], d7 = dis[s7];
        uint4v r0 = ys4[(size_t)s0 * 8 + c];
        uint4v r1 = ys4[(size_t)s1 * 8 + c];
        uint4v r2 = ys4[(size_t)s2 * 8 + c];
        uint4v r3 = ys4[(size_t)s3 * 8 + c];
        uint4v r4 = ys4[(size_t)s4 * 8 + c];
        uint4v r5 = ys4[(size_t)s5 * 8 + c];
        uint4v r6 = ys4[(size_t)s6 * 8 + c];
        uint4v r7 = ys4[(size_t)s7 * 8 + c];
        acc8s(acc, r0, d0); acc8s(acc, r1, d1); acc8s(acc, r2, d2); acc8s(acc, r3, d3);
        acc8s(acc, r4, d4); acc8s(acc, r5, d5); acc8s(acc, r6, d6); acc8s(acc, r7, d7);
    }
    for (; i < end; ++i) {
        int s = csr_src[i];
        acc8s(acc, ys4[(size_t)s * 8 + c], dis[s]);
    }
    float ds = dnd;
    const float4 bv0 = *(const float4*)&b1[c * 8];
    const float4 bv1 = *(const float4*)&b1[c * 8 + 4];
    // h row (fp32, bias + relu) -> per-wave LDS exchange (same-wave, no barrier)
    float* hrow = &hbuf[(t >> 3) * 68];
    float4 h0, h1;
    h0.x = fmaxf(fmaf(ds, acc[0], bv0.x), 0.f);
    h0.y = fmaxf(fmaf(ds, acc[1], bv0.y), 0.f);
    h0.z = fmaxf(fmaf(ds, acc[2], bv0.z), 0.f);
    h0.w = fmaxf(fmaf(ds, acc[3], bv0.w), 0.f);
    h1.x = fmaxf(fmaf(ds, acc[4], bv1.x), 0.f);
    h1.y = fmaxf(fmaf(ds, acc[5], bv1.y), 0.f);
    h1.z = fmaxf(fmaf(ds, acc[6], bv1.z), 0.f);
    h1.w = fmaxf(fmaf(ds, acc[7], bv1.w), 0.f);
    *(float4*)&hrow[c * 8]     = h0;
    *(float4*)&hrow[c * 8 + 4] = h1;
    // z[c*4 .. c*4+3] = ds * sum_k h[k] * W2[k][n]
    float p0 = 0.f, p1 = 0.f, p2 = 0.f, p3 = 0.f;
#pragma unroll 8
    for (int k = 0; k < 64; ++k) {
        float hk = hrow[k];
        const float4 wr = *(const float4*)&w2s[k * 32 + c * 4];
        p0 = fmaf(hk, wr.x, p0);
        p1 = fmaf(hk, wr.y, p1);
        p2 = fmaf(hk, wr.z, p2);
        p3 = fmaf(hk, wr.w, p3);
    }
    p0 *= ds; p1 *= ds; p2 *= ds; p3 *= ds;
    unsigned int* zp = ys2 + (size_t)nd * 16 + c * 2;  // 32 bf16 = 16 uints per node
    zp[0] = pack2(p0, p1);
    zp[1] = pack2(p2, p3);
}

// ---------------- fused gather-aggregate, dim 32 bf16 -> z bf16, unroll 8 ----------------
__global__ __launch_bounds__(256) void agg32_kernel(const uint4v* __restrict__ ys4,
                                                    const float* __restrict__ dis,
                                                    const int2* __restrict__ offs2,
                                                    const int* __restrict__ csr_src,
                                                    const float* __restrict__ b,
                                                    uint4v* __restrict__ z4) {
    int tid = blockIdx.x * 256 + threadIdx.x;
    int nd = tid >> 2, c = tid & 3;
    if (nd >= NN) return;
    int2 se = offs2[nd];
    int start = se.x, end = se.y;
    float acc[8] = {0, 0, 0, 0, 0, 0, 0, 0};
    acc8(acc, ys4[(size_t)nd * 4 + c]);
    int i = start;
    int n8 = start + ((end - start) & ~7);
    for (; i < n8; i += 8) {
        int s0 = csr_src[i],     s1 = csr_src[i + 1], s2 = csr_src[i + 2], s3 = csr_src[i + 3];
        int s4 = csr_src[i + 4], s5 = csr_src[i + 5], s6 = csr_src[i + 6], s7 = csr_src[i + 7];
        uint4v r0 = ys4[(size_t)s0 * 4 + c];
        uint4v r1 = ys4[(size_t)s1 * 4 + c];
        uint4v r2 = ys4[(size_t)s2 * 4 + c];
        uint4v r3 = ys4[(size_t)s3 * 4 + c];
        uint4v r4 = ys4[(size_t)s4 * 4 + c];
        uint4v r5 = ys4[(size_t)s5 * 4 + c];
        uint4v r6 = ys4[(size_t)s6 * 4 + c];
        uint4v r7 = ys4[(size_t)s7 * 4 + c];
        acc8(acc, r0); acc8(acc, r1); acc8(acc, r2); acc8(acc, r3);
        acc8(acc, r4); acc8(acc, r5); acc8(acc, r6); acc8(acc, r7);
    }
    for (; i < end; ++i) acc8(acc, ys4[(size_t)csr_src[i] * 4 + c]);
    float ds = dis[nd];
    const float4 bv0 = *(const float4*)&b[c * 8];
    const float4 bv1 = *(const float4*)&b[c * 8 + 4];
    uint4v o;
    o[0] = pack2(fmaf(ds, acc[0], bv0.x), fmaf(ds, acc[1], bv0.y));
    o[1] = pack2(fmaf(ds, acc[2], bv0.z), fmaf(ds, acc[3], bv0.w));
    o[2] = pack2(fmaf(ds, acc[4], bv1.x), fmaf(ds, acc[5], bv1.y));
    o[3] = pack2(fmaf(ds, acc[6], bv1.z), fmaf(ds, acc[7], bv1.w));
    z4[(size_t)nd * 4 + c] = o;
}

// ---------------- decode: sigmoid(dot(z[src], z[dst])), 4 lanes/edge, bf16 z ---------
__global__ __launch_bounds__(256) void decode_kernel(const uint4v* __restrict__ z4,
                                                     const int* __restrict__ src,
                                                     const int* __restrict__ dst,
                                                     float* __restrict__ out) {
    int tid = blockIdx.x * 256 + threadIdx.x;
    int e = tid >> 2, k = tid & 3;
    if (e >= NE) return;
    int s = src[e], d = dst[e];
    uint4v ra = z4[(size_t)s * 4 + k];
    uint4v rb = z4[(size_t)d * 4 + k];
    float acc;
    acc  = lo_f(ra[0]) * lo_f(rb[0]) + hi_f(ra[0]) * hi_f(rb[0]);
    acc += lo_f(ra[1]) * lo_f(rb[1]) + hi_f(ra[1]) * hi_f(rb[1]);
    acc += lo_f(ra[2]) * lo_f(rb[2]) + hi_f(ra[2]) * hi_f(rb[2]);
    acc += lo_f(ra[3]) * lo_f(rb[3]) + hi_f(ra[3]) * hi_f(rb[3]);
#pragma unroll
    for (int m = 2; m >= 1; m >>= 1) acc += __shfl_xor(acc, m, 4);
    if (k == 0) out[e] = 1.0f / (1.0f + expf(-acc));
}

// ---------------- launcher ----------------
extern "C" void kernel_launch(void* const* d_in, const int* in_sizes, int n_in,
                              void* d_out, int out_size, void* d_ws, size_t ws_size,
                              hipStream_t stream) {
    const float* emb = (const float*)d_in[0];
    const float* W1  = (const float*)d_in[1];
    const float* b1  = (const float*)d_in[2];
    const float* W2  = (const float*)d_in[3];
    const float* b2  = (const float*)d_in[4];
    const int*   ei  = (const int*)d_in[5];
    const int* src = ei;
    const int* dst = ei + NE;
    float* out = (float*)d_out;

    // workspace layout
    char* w = (char*)d_ws;
    int2*  offs2       = (int2*)w;          w += (size_t)NPAD * 8;         // 800KB
    float* dis         = (float*)w;         w += (size_t)NPAD * 4;
    int*   gcur        = (int*)w;           w += 2048;                     // NB cursors
    int*   csr_src     = (int*)w;           w += (size_t)NB * SLOT * 4;    // 15.3MB
    int*   staged      = (int*)w;           w += (size_t)NB * SLOT * 4;    // 15.3MB packed
    unsigned short* ysbuf = (unsigned short*)w; w += (size_t)NN * 64 * 2;  // 12.8MB bf16
    unsigned short* ys2 = (unsigned short*)w;                              // 6.4MB bf16
    unsigned short* ys1 = ysbuf;
    unsigned short* z   = ysbuf;            // overlays dead ys1 after agg64mm2

    // merged: slab-reserving scatter (782 blocks) + unscaled mm1 (391 blocks)
    hipMemsetAsync(gcur, 0, NB * 4, stream);
    scatter_mm1_kernel<<<NBLK + MMBLK, 512, 0, stream>>>(src, dst, gcur, staged, emb, W1, ys1);
    // fine counting sort -> offs2, dis, csr_src
    fine_kernel<<<NB, 1024, 0, stream>>>(staged, gcur, offs2, dis, csr_src);

    // fused: layer-1 aggregate (+dis scaling, bias, relu) + layer-2 matmul -> ys2
    agg64mm2_kernel<<<(NN * 8) / 256, 256, 0, stream>>>((const uint4v*)ys1, dis, offs2, csr_src,
                                                        b1, W2, (unsigned int*)ys2);
    // layer-2 aggregate -> z (overlays dead ys1)
    agg32_kernel<<<(NN * 4 + 255) / 256, 256, 0, stream>>>((const uint4v*)ys2, dis, offs2, csr_src, b2, (uint4v*)z);

    // decode
    decode_kernel<<<(NE * 4) / 256, 256, 0, stream>>>((const uint4v*)z, src, dst, out);
}